// Round 3
// baseline (2219.294 us; speedup 1.0000x reference)
//
#include <hip/hip_runtime.h>
#include <hip/hip_bf16.h>
#include <cstdint>
#include <cstddef>

typedef __bf16 bf16;
typedef __bf16 bf16x8 __attribute__((ext_vector_type(8)));
typedef float  f32x4  __attribute__((ext_vector_type(4)));
typedef float  f32x16 __attribute__((ext_vector_type(16)));

#define DEVI static __device__ __forceinline__

DEVI float ldf(const void* p, size_t i, bool isbf) {
  return isbf ? (float)((const bf16*)p)[i] : ((const float*)p)[i];
}

// ---------------- dtype probe: bf16 data has small magnitudes; fp32 data
// re-read as bf16 yields huge/NaN values from mantissa halves. ----------------
__global__ void probe_dtype(const void* w, int* flag) {
  int tid = threadIdx.x;
  const bf16* p = (const bf16*)w;
  float mx = 0.f;
  for (int i = tid; i < 2048; i += 64) {
    float v = fabsf((float)p[i]);
    if (!(v < 1e30f)) v = 1e30f;  // NaN/Inf -> large
    mx = fmaxf(mx, v);
  }
#pragma unroll
  for (int d = 32; d; d >>= 1) mx = fmaxf(mx, __shfl_xor(mx, d, 64));
  if (tid == 0) *flag = (mx < 100.f) ? 1 : 0;  // 1 => inputs are bf16
}

__global__ void convert_bf16(const void* src, size_t eoff, bf16* dst, int n,
                             const int* flag) {
  int i = (blockIdx.x * 256 + threadIdx.x) * 8;
  if (i >= n) return;
  if (*flag) {
    *(uint4*)(dst + i) = *(const uint4*)((const bf16*)src + eoff + i);
  } else {
    const float* s = (const float*)src + eoff + i;
    float4 a = *(const float4*)s;
    float4 b = *(const float4*)(s + 4);
    bf16 o[8] = {(bf16)a.x, (bf16)a.y, (bf16)a.z, (bf16)a.w,
                 (bf16)b.x, (bf16)b.y, (bf16)b.z, (bf16)b.w};
    *(uint4*)(dst + i) = *(const uint4*)o;
  }
}

// WT[n][k] = W[k][n]; W is [K][N] row-major, WT is [N][K] row-major (bf16 out)
__global__ void transpose_w(const void* W, bf16* WT, int K, int N, const int* flag) {
  int idx = blockIdx.x * 256 + threadIdx.x;
  if (idx >= K * N) return;
  int n = idx / K, k = idx - n * K;
  WT[idx] = (bf16)ldf(W, (size_t)k * N + n, *flag != 0);
}

// F[pair][h] = sum_p dt[d][p]*pt[phi][p]*Wb[p][h], pair = d*512+phi
__global__ __launch_bounds__(256) void build_F(const void* dt, const void* pt,
                                               const void* Wb, bf16* F,
                                               const int* flag) {
  int pair = blockIdx.x * 256 + threadIdx.x;
  int d = pair >> 9, ph = pair & 511;
  bool isbf = (*flag != 0);
  float acc[8] = {0, 0, 0, 0, 0, 0, 0, 0};
#pragma unroll
  for (int p = 0; p < 32; ++p) {
    float pe = ldf(dt, (size_t)d * 32 + p, isbf) * ldf(pt, (size_t)ph * 32 + p, isbf);
#pragma unroll
    for (int hh = 0; hh < 8; ++hh) acc[hh] += pe * ldf(Wb, (size_t)p * 8 + hh, isbf);
  }
#pragma unroll
  for (int hh = 0; hh < 8; ++hh) F[(size_t)pair * 8 + hh] = (bf16)acc[hh];
}

// bias[m][h][i*32+j] = F[d*512+phi][h]   (m local to chunk; dist/phi pre-offset)
__global__ __launch_bounds__(256) void build_bias(const int* __restrict__ dist,
                                                  const int* __restrict__ phi,
                                                  const bf16* __restrict__ F,
                                                  bf16* __restrict__ bias) {
  const int m = blockIdx.x;
#pragma unroll
  for (int it = 0; it < 4; ++it) {
    int e = it * 256 + threadIdx.x;
    int d = dist[(size_t)m * 1024 + e];
    int ph = phi[(size_t)m * 1024 + e];
    uint4 fv = *(const uint4*)(F + ((size_t)d * 512 + ph) * 8);
    const bf16* fe = (const bf16*)&fv;
#pragma unroll
    for (int hh = 0; hh < 8; ++hh)
      bias[((size_t)m * 8 + hh) * 1024 + e] = fe[hh];
  }
}

// C[(row0+M), N] = A[M,K] @ BT[N,K]^T, 128x128 tile, BK=32, 4 waves,
// 16x16x32 bf16 MFMA. Reg-staged LDS (no global_load_lds this round).
template <int DO_SILU, int OUT_DUAL>
__global__ __launch_bounds__(256) void gemm_bt(const bf16* __restrict__ A,
                                               const bf16* __restrict__ BT,
                                               void* __restrict__ Cv, int N, int K,
                                               const int* flag, size_t row0) {
  __shared__ bf16 As[128 * 32];
  __shared__ bf16 Bs[128 * 32];
  const int bn = blockIdx.x * 128;
  const int bm = blockIdx.y * 128;
  const int tid = threadIdx.x;
  const int lane = tid & 63;
  const int wave = tid >> 6;
  const int wr = (wave >> 1) * 64, wc = (wave & 1) * 64;
  const int srow = tid >> 2, skk = (tid & 3) * 8;
  const size_t sK = (size_t)K;
  const int kq = (lane >> 4) * 8;
  const int fr = lane & 15;
  f32x4 acc[4][4] = {};
  for (int k0 = 0; k0 < K; k0 += 32) {
    bf16x8 a0 = *(const bf16x8*)(A + (size_t)(bm + srow) * sK + k0 + skk);
    bf16x8 a1 = *(const bf16x8*)(A + (size_t)(bm + 64 + srow) * sK + k0 + skk);
    bf16x8 b0 = *(const bf16x8*)(BT + (size_t)(bn + srow) * sK + k0 + skk);
    bf16x8 b1 = *(const bf16x8*)(BT + (size_t)(bn + 64 + srow) * sK + k0 + skk);
    __syncthreads();  // previous tile fully consumed
    *(bf16x8*)(As + srow * 32 + skk) = a0;
    *(bf16x8*)(As + (64 + srow) * 32 + skk) = a1;
    *(bf16x8*)(Bs + srow * 32 + skk) = b0;
    *(bf16x8*)(Bs + (64 + srow) * 32 + skk) = b1;
    __syncthreads();
    bf16x8 af[4], bfr[4];
#pragma unroll
    for (int i = 0; i < 4; ++i)
      af[i] = *(const bf16x8*)(As + (wr + i * 16 + fr) * 32 + kq);
#pragma unroll
    for (int j = 0; j < 4; ++j)
      bfr[j] = *(const bf16x8*)(Bs + (wc + j * 16 + fr) * 32 + kq);
#pragma unroll
    for (int i = 0; i < 4; ++i)
#pragma unroll
      for (int j = 0; j < 4; ++j)
        acc[i][j] = __builtin_amdgcn_mfma_f32_16x16x32_bf16(af[i], bfr[j], acc[i][j], 0, 0, 0);
  }
  const int fq = (lane >> 4) * 4;
  const bool write_f32 = OUT_DUAL && flag && (*flag == 0);
#pragma unroll
  for (int i = 0; i < 4; ++i)
#pragma unroll
    for (int j = 0; j < 4; ++j)
#pragma unroll
      for (int r = 0; r < 4; ++r) {
        size_t row = row0 + (size_t)(bm + wr + i * 16 + fq + r);
        size_t col = (size_t)(bn + wc + j * 16 + fr);
        float v = acc[i][j][r];
        if (DO_SILU) v = v / (1.f + __expf(-v));
        if (OUT_DUAL && write_f32)
          ((float*)Cv)[row * N + col] = v;
        else
          ((bf16*)Cv)[row * N + col] = (bf16)v;
      }
}

// per-problem fused attention: block = m (chunk-local), wave = head
__global__ __launch_bounds__(512) void attn_fused(const bf16* __restrict__ QKV,
                                                  const bf16* __restrict__ bias,
                                                  bf16* __restrict__ O) {
  const int m = blockIdx.x;
  const int lane = threadIdx.x & 63;
  const int h = threadIdx.x >> 6;
  __shared__ bf16 Vs[8][32 * 64];
  __shared__ bf16 Ps[8][32 * 32];
  const size_t rowbase = (size_t)m * 32 * 1536;
  // stage V [32][64] (wave-private slice)
#pragma unroll
  for (int rr = 0; rr < 4; ++rr) {
    int e = rr * 512 + lane * 8;
    int i = e >> 6, c = e & 63;
    *(uint4*)&Vs[h][e] =
        *(const uint4*)(QKV + rowbase + (size_t)i * 1536 + 1024 + h * 64 + c);
  }
  const int fr = lane & 31;
  const int kq = (lane >> 5) * 8;
  bf16x8 qf[4], kf[4];
#pragma unroll
  for (int kk = 0; kk < 4; ++kk) {
    qf[kk] = *(const bf16x8*)(QKV + rowbase + (size_t)fr * 1536 + h * 64 + kk * 16 + kq);
    kf[kk] = *(const bf16x8*)(QKV + rowbase + (size_t)fr * 1536 + 512 + h * 64 + kk * 16 + kq);
  }
  f32x16 s = {};
#pragma unroll
  for (int kk = 0; kk < 4; ++kk)
    s = __builtin_amdgcn_mfma_f32_32x32x16_bf16(qf[kk], kf[kk], s, 0, 0, 0);
  // D layout: col j = lane&31, row i = (r&3)+8*(r>>2)+4*(lane>>5)
  const bf16* bp = bias + ((size_t)m * 8 + h) * 1024;
  const int ri = 4 * (lane >> 5);
  float p[16];
#pragma unroll
  for (int r = 0; r < 16; ++r) {
    int i = (r & 3) + 8 * (r >> 2) + ri;
    p[r] = s[r] * 0.125f + (float)bp[i * 32 + fr];
  }
#pragma unroll
  for (int r = 0; r < 16; ++r) {
    float mx = p[r];
#pragma unroll
    for (int d = 16; d; d >>= 1) mx = fmaxf(mx, __shfl_xor(mx, d, 64));
    float e = __expf(p[r] - mx);
    float sum = e;
#pragma unroll
    for (int d = 16; d; d >>= 1) sum += __shfl_xor(sum, d, 64);
    p[r] = e / sum;
  }
#pragma unroll
  for (int r = 0; r < 16; ++r) {
    int i = (r & 3) + 8 * (r >> 2) + ri;
    Ps[h][i * 32 + fr] = (bf16)p[r];
  }
  __syncthreads();  // order LDS P/V writes before cross-lane reads
  bf16x8 pf[2];
#pragma unroll
  for (int kk = 0; kk < 2; ++kk)
    pf[kk] = *(const bf16x8*)(&Ps[h][fr * 32 + kk * 16 + kq]);
  f32x16 o0 = {}, o1 = {};
#pragma unroll
  for (int kk = 0; kk < 2; ++kk) {
    bf16x8 v0, v1;
#pragma unroll
    for (int e = 0; e < 8; ++e) {
      v0[e] = Vs[h][(kk * 16 + kq + e) * 64 + fr];
      v1[e] = Vs[h][(kk * 16 + kq + e) * 64 + 32 + fr];
    }
    o0 = __builtin_amdgcn_mfma_f32_32x32x16_bf16(pf[kk], v0, o0, 0, 0, 0);
    o1 = __builtin_amdgcn_mfma_f32_32x32x16_bf16(pf[kk], v1, o1, 0, 0, 0);
  }
  bf16* op = O + (size_t)m * 32 * 512 + h * 64;
#pragma unroll
  for (int r = 0; r < 16; ++r) {
    int i = (r & 3) + 8 * (r >> 2) + ri;
    op[(size_t)i * 512 + fr] = (bf16)o0[r];
    op[(size_t)i * 512 + 32 + fr] = (bf16)o1[r];
  }
}

// out = LN(X+Y)*g+b ; one wave per 512-wide row (X==out aliasing is safe)
__global__ __launch_bounds__(256) void ln_fused(const bf16* __restrict__ X,
                                                const bf16* __restrict__ Y,
                                                const bf16* __restrict__ gb, int gboff,
                                                bf16* __restrict__ out) {
  const int row = blockIdx.x * 4 + (threadIdx.x >> 6);
  const int lane = threadIdx.x & 63;
  uint4 xr = *(const uint4*)(X + (size_t)row * 512 + lane * 8);
  uint4 yr = *(const uint4*)(Y + (size_t)row * 512 + lane * 8);
  const bf16* xe = (const bf16*)&xr;
  const bf16* ye = (const bf16*)&yr;
  float v[8];
  float sum = 0.f;
#pragma unroll
  for (int e = 0; e < 8; ++e) { v[e] = (float)xe[e] + (float)ye[e]; sum += v[e]; }
#pragma unroll
  for (int d = 32; d; d >>= 1) sum += __shfl_xor(sum, d, 64);
  float mean = sum * (1.f / 512.f);
  float var = 0.f;
#pragma unroll
  for (int e = 0; e < 8; ++e) { float t = v[e] - mean; var += t * t; }
#pragma unroll
  for (int d = 32; d; d >>= 1) var += __shfl_xor(var, d, 64);
  float rstd = rsqrtf(var * (1.f / 512.f) + 1e-5f);
  uint4 gr = *(const uint4*)(gb + gboff + lane * 8);
  uint4 br = *(const uint4*)(gb + gboff + 512 + lane * 8);
  const bf16* ge = (const bf16*)&gr;
  const bf16* be = (const bf16*)&br;
  bf16 o[8];
#pragma unroll
  for (int e = 0; e < 8; ++e)
    o[e] = (bf16)((v[e] - mean) * rstd * (float)ge[e] + (float)be[e]);
  *(uint4*)(out + (size_t)row * 512 + lane * 8) = *(const uint4*)o;
}

extern "C" void kernel_launch(void* const* d_in, const int* in_sizes, int n_in,
                              void* d_out, int out_size, void* d_ws, size_t ws_size,
                              hipStream_t stream) {
  const int T = 131072;  // B*N*NH total rows
  const void* x    = d_in[0];
  const int*  dist = (const int*)d_in[1];
  const int*  phiI = (const int*)d_in[2];
  const void* Win  = d_in[3];
  const void* dtab = d_in[4];
  const void* ptab = d_in[5];
  const void* Wb   = d_in[6];
  const void* Wq   = d_in[7];
  const void* Wk   = d_in[8];
  const void* Wv   = d_in[9];
  const void* Wo   = d_in[10];
  const void* Wf1  = d_in[11];
  const void* Wf2  = d_in[12];
  const void* g1   = d_in[13];
  const void* b1   = d_in[14];
  const void* g2   = d_in[15];
  const void* b2   = d_in[16];
  const void* Wout = d_in[17];
  (void)in_sizes; (void)n_in; (void)out_size;

  // ---- adaptive chunking: pick largest power-of-two row chunk that fits ws
  const size_t FIXED = (size_t)16 << 20;   // transposed weights + F-table + slack
  int R = 131072;
  while (R > 1024 && FIXED + (size_t)R * 7936 > ws_size) R >>= 1;
  const int MC = R / 32;
  const int NCHUNK = T / R;

  char* wsb = (char*)d_ws;
  size_t off = 0;
  auto alloc = [&](size_t bytes) {
    char* p = wsb + off;
    off += (bytes + 511) & ~(size_t)511;
    return p;
  };
  int*  flag = (int*)alloc(4);
  bf16* gb   = (bf16*)alloc(2048 * 2);
  bf16* WinT = (bf16*)alloc((size_t)512 * 128 * 2);
  bf16* QKVT = (bf16*)alloc((size_t)1536 * 512 * 2);
  bf16* WoT  = (bf16*)alloc((size_t)512 * 512 * 2);
  bf16* Wf1T = (bf16*)alloc((size_t)2048 * 512 * 2);
  bf16* Wf2T = (bf16*)alloc((size_t)512 * 2048 * 2);
  bf16* WouT = (bf16*)alloc((size_t)128 * 512 * 2);
  bf16* Ftab = (bf16*)alloc((size_t)262144 * 8 * 2);     // 4 MB
  bf16* Xc   = (bf16*)alloc((size_t)R * 128 * 2);
  bf16* Hc   = (bf16*)alloc((size_t)R * 512 * 2);
  bf16* big  = (bf16*)alloc((size_t)R * 2048 * 2);       // QKV (1536) / FF1 (2048)
  bf16* Oc   = (bf16*)alloc((size_t)R * 512 * 2);
  bf16* AOc  = (bf16*)alloc((size_t)R * 512 * 2);
  bf16* biasc= (bf16*)alloc((size_t)MC * 8 * 1024 * 2);

  probe_dtype<<<1, 64, 0, stream>>>(Win, flag);
  convert_bf16<<<1, 256, 0, stream>>>(g1, 0, gb + 0, 512, flag);
  convert_bf16<<<1, 256, 0, stream>>>(b1, 0, gb + 512, 512, flag);
  convert_bf16<<<1, 256, 0, stream>>>(g2, 0, gb + 1024, 512, flag);
  convert_bf16<<<1, 256, 0, stream>>>(b2, 0, gb + 1536, 512, flag);
  transpose_w<<<(512 * 128 + 255) / 256, 256, 0, stream>>>(Win, WinT, 128, 512, flag);
  transpose_w<<<(512 * 512 + 255) / 256, 256, 0, stream>>>(Wq, QKVT, 512, 512, flag);
  transpose_w<<<(512 * 512 + 255) / 256, 256, 0, stream>>>(Wk, QKVT + 512 * 512, 512, 512, flag);
  transpose_w<<<(512 * 512 + 255) / 256, 256, 0, stream>>>(Wv, QKVT + 1024 * 512, 512, 512, flag);
  transpose_w<<<(512 * 512 + 255) / 256, 256, 0, stream>>>(Wo, WoT, 512, 512, flag);
  transpose_w<<<(2048 * 512 + 255) / 256, 256, 0, stream>>>(Wf1, Wf1T, 512, 2048, flag);
  transpose_w<<<(2048 * 512 + 255) / 256, 256, 0, stream>>>(Wf2, Wf2T, 2048, 512, flag);
  transpose_w<<<(128 * 512 + 255) / 256, 256, 0, stream>>>(Wout, WouT, 512, 128, flag);
  build_F<<<262144 / 256, 256, 0, stream>>>(dtab, ptab, Wb, Ftab, flag);

  dim3 blk(256);
  for (int c = 0; c < NCHUNK; ++c) {
    const size_t rowoff = (size_t)c * R;
    const size_t moff = (size_t)c * MC;
    // x chunk -> bf16
    convert_bf16<<<(R * 128 / 8 + 255) / 256, 256, 0, stream>>>(x, rowoff * 128, Xc, R * 128, flag);
    // input proj: Hc = Xc @ W_in
    gemm_bt<0, 0><<<dim3(4, R / 128), blk, 0, stream>>>(Xc, WinT, Hc, 512, 128, nullptr, 0);
    // QKV chunk
    gemm_bt<0, 0><<<dim3(12, R / 128), blk, 0, stream>>>(Hc, QKVT, big, 1536, 512, nullptr, 0);
    build_bias<<<MC, 256, 0, stream>>>(dist + moff * 1024, phiI + moff * 1024, Ftab, biasc);
    attn_fused<<<MC, 512, 0, stream>>>(big, biasc, Oc);
    // att_out chunk
    gemm_bt<0, 0><<<dim3(4, R / 128), blk, 0, stream>>>(Oc, WoT, AOc, 512, 512, nullptr, 0);
    // h1 = LN(h + att_out), in place in Hc
    ln_fused<<<R / 4, 256, 0, stream>>>(Hc, AOc, gb, 0, Hc);
    // FF1 with SiLU
    gemm_bt<1, 0><<<dim3(16, R / 128), blk, 0, stream>>>(Hc, Wf1T, big, 2048, 512, nullptr, 0);
    // FF2
    gemm_bt<0, 0><<<dim3(4, R / 128), blk, 0, stream>>>(big, Wf2T, AOc, 512, 2048, nullptr, 0);
    // h2 = LN(h1 + ff), in place in Hc
    ln_fused<<<R / 4, 256, 0, stream>>>(Hc, AOc, gb, 1024, Hc);
    // output proj -> d_out rows [rowoff, rowoff+R)
    gemm_bt<0, 1><<<dim3(1, R / 128), blk, 0, stream>>>(Hc, WouT, d_out, 128, 512, flag, rowoff);
  }
}

// Round 4
// 2216.300 us; speedup vs baseline: 1.0014x; 1.0014x over previous
//
#include <hip/hip_runtime.h>
#include <hip/hip_bf16.h>
#include <cstdint>
#include <cstddef>

typedef __bf16 bf16;
typedef __bf16 bf16x8 __attribute__((ext_vector_type(8)));
typedef float  f32x4  __attribute__((ext_vector_type(4)));
typedef float  f32x16 __attribute__((ext_vector_type(16)));

#define DEVI static __device__ __forceinline__

DEVI void gload_lds16(const void* g, void* l) {
  __builtin_amdgcn_global_load_lds(
      (const __attribute__((address_space(1))) uint32_t*)(uintptr_t)g,
      (__attribute__((address_space(3))) uint32_t*)(uint32_t)(uintptr_t)l,
      16, 0, 0);
}

DEVI float ldf(const void* p, size_t i, bool isbf) {
  return isbf ? (float)((const bf16*)p)[i] : ((const float*)p)[i];
}

// ---------------- dtype probe: bf16 data has small magnitudes; fp32 data
// re-read as bf16 yields huge/NaN values from mantissa halves. ----------------
__global__ void probe_dtype(const void* w, int* flag) {
  int tid = threadIdx.x;
  const bf16* p = (const bf16*)w;
  float mx = 0.f;
  for (int i = tid; i < 2048; i += 64) {
    float v = fabsf((float)p[i]);
    if (!(v < 1e30f)) v = 1e30f;  // NaN/Inf -> large
    mx = fmaxf(mx, v);
  }
#pragma unroll
  for (int d = 32; d; d >>= 1) mx = fmaxf(mx, __shfl_xor(mx, d, 64));
  if (tid == 0) *flag = (mx < 100.f) ? 1 : 0;  // 1 => inputs are bf16
}

__global__ void convert_bf16(const void* src, size_t eoff, bf16* dst, int n,
                             const int* flag) {
  int i = (blockIdx.x * 256 + threadIdx.x) * 8;
  if (i >= n) return;
  if (*flag) {
    *(uint4*)(dst + i) = *(const uint4*)((const bf16*)src + eoff + i);
  } else {
    const float* s = (const float*)src + eoff + i;
    float4 a = *(const float4*)s;
    float4 b = *(const float4*)(s + 4);
    bf16 o[8] = {(bf16)a.x, (bf16)a.y, (bf16)a.z, (bf16)a.w,
                 (bf16)b.x, (bf16)b.y, (bf16)b.z, (bf16)b.w};
    *(uint4*)(dst + i) = *(const uint4*)o;
  }
}

// canonical f32 copy of a (possibly bf16) input
__global__ void convert_f32(const void* src, float* dst, int n, const int* flag) {
  int i = blockIdx.x * 256 + threadIdx.x;
  if (i >= n) return;
  dst[i] = ldf(src, i, *flag != 0);
}

// WT[n][k] = W[k][n]; W is [K][N] row-major, WT is [N][K] row-major (bf16 out)
__global__ void transpose_w(const void* W, bf16* WT, int K, int N, const int* flag) {
  int idx = blockIdx.x * 256 + threadIdx.x;
  if (idx >= K * N) return;
  int n = idx / K, k = idx - n * K;
  WT[idx] = (bf16)ldf(W, (size_t)k * N + n, *flag != 0);
}

// F[pair][h] = sum_p dt[d][p]*pt[phi][p]*Wb[p][h], pair = d*512+phi
// vectorized: f32 tables, W_bias staged in LDS
__global__ __launch_bounds__(256) void build_F(const float* __restrict__ dt32,
                                               const float* __restrict__ pt32,
                                               const float* __restrict__ Wb32,
                                               bf16* __restrict__ F) {
  __shared__ float WbS[256];
  WbS[threadIdx.x] = Wb32[threadIdx.x];
  __syncthreads();
  int pair = blockIdx.x * 256 + threadIdx.x;
  int d = pair >> 9, ph = pair & 511;
  const float4* dtv = (const float4*)(dt32 + (size_t)d * 32);
  const float4* ptv = (const float4*)(pt32 + (size_t)ph * 32);
  float acc[8] = {0, 0, 0, 0, 0, 0, 0, 0};
#pragma unroll
  for (int q = 0; q < 8; ++q) {
    float4 a = dtv[q], b = ptv[q];
    float pe[4] = {a.x * b.x, a.y * b.y, a.z * b.z, a.w * b.w};
#pragma unroll
    for (int e = 0; e < 4; ++e)
#pragma unroll
      for (int hh = 0; hh < 8; ++hh) acc[hh] += pe[e] * WbS[(q * 4 + e) * 8 + hh];
  }
  bf16 o[8];
#pragma unroll
  for (int hh = 0; hh < 8; ++hh) o[hh] = (bf16)acc[hh];
  *(uint4*)(F + (size_t)pair * 8) = *(const uint4*)o;
}

// bias[m][h][i*32+j] = F[d*512+phi][h]   (m local to chunk; dist/phi pre-offset)
__global__ __launch_bounds__(256) void build_bias(const int* __restrict__ dist,
                                                  const int* __restrict__ phi,
                                                  const bf16* __restrict__ F,
                                                  bf16* __restrict__ bias) {
  const int m = blockIdx.x;
#pragma unroll
  for (int it = 0; it < 4; ++it) {
    int e = it * 256 + threadIdx.x;
    int d = dist[(size_t)m * 1024 + e];
    int ph = phi[(size_t)m * 1024 + e];
    uint4 fv = *(const uint4*)(F + ((size_t)d * 512 + ph) * 8);
    const bf16* fe = (const bf16*)&fv;
#pragma unroll
    for (int hh = 0; hh < 8; ++hh)
      bias[((size_t)m * 8 + hh) * 1024 + e] = fe[hh];
  }
}

// C[(row0+M), N] = A[M,K] @ BT[N,K]^T, 128x128 tile, BK=32, 4 waves,
// 16x16x32 bf16 MFMA, global_load_lds width-16 staging (m97 structure).
template <int DO_SILU, int OUT_DUAL>
__global__ __launch_bounds__(256) void gemm_bt(const bf16* __restrict__ A,
                                               const bf16* __restrict__ BT,
                                               void* __restrict__ Cv, int N, int K,
                                               const int* flag, size_t row0) {
  __shared__ bf16 As[128 * 32];
  __shared__ bf16 Bs[128 * 32];
  const int bn = blockIdx.x * 128;
  const int bm = blockIdx.y * 128;
  const int tid = threadIdx.x;
  const int lane = tid & 63;
  const int wave = tid >> 6;
  const int wr = (wave >> 1) * 64, wc = (wave & 1) * 64;
  const int srow = tid >> 2, skk = (tid & 3) * 8;
  const size_t sK = (size_t)K;
  const int kq = (lane >> 4) * 8;
  const int fr = lane & 15;
  f32x4 acc[4][4] = {};
  for (int k0 = 0; k0 < K; k0 += 32) {
    __syncthreads();  // previous tile fully consumed
    gload_lds16(A + (size_t)(bm + srow) * sK + k0 + skk, As + tid * 8);
    gload_lds16(A + (size_t)(bm + 64 + srow) * sK + k0 + skk, As + 2048 + tid * 8);
    gload_lds16(BT + (size_t)(bn + srow) * sK + k0 + skk, Bs + tid * 8);
    gload_lds16(BT + (size_t)(bn + 64 + srow) * sK + k0 + skk, Bs + 2048 + tid * 8);
    __syncthreads();
    bf16x8 af[4], bfr[4];
#pragma unroll
    for (int i = 0; i < 4; ++i)
      af[i] = *(const bf16x8*)(As + (wr + i * 16 + fr) * 32 + kq);
#pragma unroll
    for (int j = 0; j < 4; ++j)
      bfr[j] = *(const bf16x8*)(Bs + (wc + j * 16 + fr) * 32 + kq);
#pragma unroll
    for (int i = 0; i < 4; ++i)
#pragma unroll
      for (int j = 0; j < 4; ++j)
        acc[i][j] = __builtin_amdgcn_mfma_f32_16x16x32_bf16(af[i], bfr[j], acc[i][j], 0, 0, 0);
  }
  const int fq = (lane >> 4) * 4;
  const bool write_f32 = OUT_DUAL && flag && (*flag == 0);
#pragma unroll
  for (int i = 0; i < 4; ++i)
#pragma unroll
    for (int j = 0; j < 4; ++j)
#pragma unroll
      for (int r = 0; r < 4; ++r) {
        size_t row = row0 + (size_t)(bm + wr + i * 16 + fq + r);
        size_t col = (size_t)(bn + wc + j * 16 + fr);
        float v = acc[i][j][r];
        if (DO_SILU) v = v / (1.f + __expf(-v));
        if (OUT_DUAL && write_f32)
          ((float*)Cv)[row * N + col] = v;
        else
          ((bf16*)Cv)[row * N + col] = (bf16)v;
      }
}

// per-problem fused attention: block = m (chunk-local), wave = head
__global__ __launch_bounds__(512) void attn_fused(const bf16* __restrict__ QKV,
                                                  const bf16* __restrict__ bias,
                                                  bf16* __restrict__ O) {
  const int m = blockIdx.x;
  const int lane = threadIdx.x & 63;
  const int h = threadIdx.x >> 6;
  __shared__ bf16 Vs[8][32 * 64];
  __shared__ bf16 Ps[8][32 * 32];
  const size_t rowbase = (size_t)m * 32 * 1536;
  // stage V [32][64] (wave-private slice)
#pragma unroll
  for (int rr = 0; rr < 4; ++rr) {
    int e = rr * 512 + lane * 8;
    int i = e >> 6, c = e & 63;
    *(uint4*)&Vs[h][e] =
        *(const uint4*)(QKV + rowbase + (size_t)i * 1536 + 1024 + h * 64 + c);
  }
  const int fr = lane & 31;
  const int kq = (lane >> 5) * 8;
  bf16x8 qf[4], kf[4];
#pragma unroll
  for (int kk = 0; kk < 4; ++kk) {
    qf[kk] = *(const bf16x8*)(QKV + rowbase + (size_t)fr * 1536 + h * 64 + kk * 16 + kq);
    kf[kk] = *(const bf16x8*)(QKV + rowbase + (size_t)fr * 1536 + 512 + h * 64 + kk * 16 + kq);
  }
  f32x16 s = {};
#pragma unroll
  for (int kk = 0; kk < 4; ++kk)
    s = __builtin_amdgcn_mfma_f32_32x32x16_bf16(qf[kk], kf[kk], s, 0, 0, 0);
  // D layout: col j = lane&31, row i = (r&3)+8*(r>>2)+4*(lane>>5)
  const bf16* bp = bias + ((size_t)m * 8 + h) * 1024;
  const int ri = 4 * (lane >> 5);
  float p[16];
#pragma unroll
  for (int r = 0; r < 16; ++r) {
    int i = (r & 3) + 8 * (r >> 2) + ri;
    p[r] = s[r] * 0.125f + (float)bp[i * 32 + fr];
  }
#pragma unroll
  for (int r = 0; r < 16; ++r) {
    float mx = p[r];
#pragma unroll
    for (int d = 16; d; d >>= 1) mx = fmaxf(mx, __shfl_xor(mx, d, 64));
    float e = __expf(p[r] - mx);
    float sum = e;
#pragma unroll
    for (int d = 16; d; d >>= 1) sum += __shfl_xor(sum, d, 64);
    p[r] = e / sum;
  }
#pragma unroll
  for (int r = 0; r < 16; ++r) {
    int i = (r & 3) + 8 * (r >> 2) + ri;
    Ps[h][i * 32 + fr] = (bf16)p[r];
  }
  __syncthreads();  // order LDS P/V writes before cross-lane reads
  bf16x8 pf[2];
#pragma unroll
  for (int kk = 0; kk < 2; ++kk)
    pf[kk] = *(const bf16x8*)(&Ps[h][fr * 32 + kk * 16 + kq]);
  f32x16 o0 = {}, o1 = {};
#pragma unroll
  for (int kk = 0; kk < 2; ++kk) {
    bf16x8 v0, v1;
#pragma unroll
    for (int e = 0; e < 8; ++e) {
      v0[e] = Vs[h][(kk * 16 + kq + e) * 64 + fr];
      v1[e] = Vs[h][(kk * 16 + kq + e) * 64 + 32 + fr];
    }
    o0 = __builtin_amdgcn_mfma_f32_32x32x16_bf16(pf[kk], v0, o0, 0, 0, 0);
    o1 = __builtin_amdgcn_mfma_f32_32x32x16_bf16(pf[kk], v1, o1, 0, 0, 0);
  }
  bf16* op = O + (size_t)m * 32 * 512 + h * 64;
#pragma unroll
  for (int r = 0; r < 16; ++r) {
    int i = (r & 3) + 8 * (r >> 2) + ri;
    op[(size_t)i * 512 + fr] = (bf16)o0[r];
    op[(size_t)i * 512 + 32 + fr] = (bf16)o1[r];
  }
}

// out = LN(X+Y)*g+b ; one wave per 512-wide row (X==out aliasing is safe)
__global__ __launch_bounds__(256) void ln_fused(const bf16* __restrict__ X,
                                                const bf16* __restrict__ Y,
                                                const bf16* __restrict__ gb, int gboff,
                                                bf16* __restrict__ out) {
  const int row = blockIdx.x * 4 + (threadIdx.x >> 6);
  const int lane = threadIdx.x & 63;
  uint4 xr = *(const uint4*)(X + (size_t)row * 512 + lane * 8);
  uint4 yr = *(const uint4*)(Y + (size_t)row * 512 + lane * 8);
  const bf16* xe = (const bf16*)&xr;
  const bf16* ye = (const bf16*)&yr;
  float v[8];
  float sum = 0.f;
#pragma unroll
  for (int e = 0; e < 8; ++e) { v[e] = (float)xe[e] + (float)ye[e]; sum += v[e]; }
#pragma unroll
  for (int d = 32; d; d >>= 1) sum += __shfl_xor(sum, d, 64);
  float mean = sum * (1.f / 512.f);
  float var = 0.f;
#pragma unroll
  for (int e = 0; e < 8; ++e) { float t = v[e] - mean; var += t * t; }
#pragma unroll
  for (int d = 32; d; d >>= 1) var += __shfl_xor(var, d, 64);
  float rstd = rsqrtf(var * (1.f / 512.f) + 1e-5f);
  uint4 gr = *(const uint4*)(gb + gboff + lane * 8);
  uint4 br = *(const uint4*)(gb + gboff + 512 + lane * 8);
  const bf16* ge = (const bf16*)&gr;
  const bf16* be = (const bf16*)&br;
  bf16 o[8];
#pragma unroll
  for (int e = 0; e < 8; ++e)
    o[e] = (bf16)((v[e] - mean) * rstd * (float)ge[e] + (float)be[e]);
  *(uint4*)(out + (size_t)row * 512 + lane * 8) = *(const uint4*)o;
}

extern "C" void kernel_launch(void* const* d_in, const int* in_sizes, int n_in,
                              void* d_out, int out_size, void* d_ws, size_t ws_size,
                              hipStream_t stream) {
  const int T = 131072;  // B*N*NH total rows
  const void* x    = d_in[0];
  const int*  dist = (const int*)d_in[1];
  const int*  phiI = (const int*)d_in[2];
  const void* Win  = d_in[3];
  const void* dtab = d_in[4];
  const void* ptab = d_in[5];
  const void* Wb   = d_in[6];
  const void* Wq   = d_in[7];
  const void* Wk   = d_in[8];
  const void* Wv   = d_in[9];
  const void* Wo   = d_in[10];
  const void* Wf1  = d_in[11];
  const void* Wf2  = d_in[12];
  const void* g1   = d_in[13];
  const void* b1   = d_in[14];
  const void* g2   = d_in[15];
  const void* b2   = d_in[16];
  const void* Wout = d_in[17];
  (void)in_sizes; (void)n_in; (void)out_size;

  // ---- adaptive chunking: pick largest power-of-two row chunk that fits ws
  const size_t FIXED = (size_t)16 << 20;   // transposed weights + F-table + slack
  int R = 131072;
  while (R > 1024 && FIXED + (size_t)R * 7936 > ws_size) R >>= 1;
  const int MC = R / 32;
  const int NCHUNK = T / R;

  char* wsb = (char*)d_ws;
  size_t off = 0;
  auto alloc = [&](size_t bytes) {
    char* p = wsb + off;
    off += (bytes + 511) & ~(size_t)511;
    return p;
  };
  int*  flag = (int*)alloc(4);
  bf16* gb   = (bf16*)alloc(2048 * 2);
  float* dt32 = (float*)alloc((size_t)512 * 32 * 4);
  float* pt32 = (float*)alloc((size_t)512 * 32 * 4);
  float* Wb32 = (float*)alloc(256 * 4);
  bf16* WinT = (bf16*)alloc((size_t)512 * 128 * 2);
  bf16* QKVT = (bf16*)alloc((size_t)1536 * 512 * 2);
  bf16* WoT  = (bf16*)alloc((size_t)512 * 512 * 2);
  bf16* Wf1T = (bf16*)alloc((size_t)2048 * 512 * 2);
  bf16* Wf2T = (bf16*)alloc((size_t)512 * 2048 * 2);
  bf16* WouT = (bf16*)alloc((size_t)128 * 512 * 2);
  bf16* Ftab = (bf16*)alloc((size_t)262144 * 8 * 2);     // 4 MB
  bf16* Xc   = (bf16*)alloc((size_t)R * 128 * 2);
  bf16* Hc   = (bf16*)alloc((size_t)R * 512 * 2);
  bf16* big  = (bf16*)alloc((size_t)R * 2048 * 2);       // QKV (1536) / FF1 (2048)
  bf16* Oc   = (bf16*)alloc((size_t)R * 512 * 2);
  bf16* AOc  = (bf16*)alloc((size_t)R * 512 * 2);
  bf16* biasc= (bf16*)alloc((size_t)MC * 8 * 1024 * 2);

  probe_dtype<<<1, 64, 0, stream>>>(Win, flag);
  convert_bf16<<<1, 256, 0, stream>>>(g1, 0, gb + 0, 512, flag);
  convert_bf16<<<1, 256, 0, stream>>>(b1, 0, gb + 512, 512, flag);
  convert_bf16<<<1, 256, 0, stream>>>(g2, 0, gb + 1024, 512, flag);
  convert_bf16<<<1, 256, 0, stream>>>(b2, 0, gb + 1536, 512, flag);
  convert_f32<<<64, 256, 0, stream>>>(dtab, dt32, 512 * 32, flag);
  convert_f32<<<64, 256, 0, stream>>>(ptab, pt32, 512 * 32, flag);
  convert_f32<<<1, 256, 0, stream>>>(Wb, Wb32, 256, flag);
  transpose_w<<<(512 * 128 + 255) / 256, 256, 0, stream>>>(Win, WinT, 128, 512, flag);
  transpose_w<<<(512 * 512 + 255) / 256, 256, 0, stream>>>(Wq, QKVT, 512, 512, flag);
  transpose_w<<<(512 * 512 + 255) / 256, 256, 0, stream>>>(Wk, QKVT + 512 * 512, 512, 512, flag);
  transpose_w<<<(512 * 512 + 255) / 256, 256, 0, stream>>>(Wv, QKVT + 1024 * 512, 512, 512, flag);
  transpose_w<<<(512 * 512 + 255) / 256, 256, 0, stream>>>(Wo, WoT, 512, 512, flag);
  transpose_w<<<(2048 * 512 + 255) / 256, 256, 0, stream>>>(Wf1, Wf1T, 512, 2048, flag);
  transpose_w<<<(2048 * 512 + 255) / 256, 256, 0, stream>>>(Wf2, Wf2T, 2048, 512, flag);
  transpose_w<<<(128 * 512 + 255) / 256, 256, 0, stream>>>(Wout, WouT, 512, 128, flag);
  build_F<<<262144 / 256, 256, 0, stream>>>(dt32, pt32, Wb32, Ftab);

  dim3 blk(256);
  for (int c = 0; c < NCHUNK; ++c) {
    const size_t rowoff = (size_t)c * R;
    const size_t moff = (size_t)c * MC;
    // x chunk -> bf16
    convert_bf16<<<(R * 128 / 8 + 255) / 256, 256, 0, stream>>>(x, rowoff * 128, Xc, R * 128, flag);
    // input proj: Hc = Xc @ W_in
    gemm_bt<0, 0><<<dim3(4, R / 128), blk, 0, stream>>>(Xc, WinT, Hc, 512, 128, nullptr, 0);
    // QKV chunk
    gemm_bt<0, 0><<<dim3(12, R / 128), blk, 0, stream>>>(Hc, QKVT, big, 1536, 512, nullptr, 0);
    build_bias<<<MC, 256, 0, stream>>>(dist + moff * 1024, phiI + moff * 1024, Ftab, biasc);
    attn_fused<<<MC, 512, 0, stream>>>(big, biasc, Oc);
    // att_out chunk
    gemm_bt<0, 0><<<dim3(4, R / 128), blk, 0, stream>>>(Oc, WoT, AOc, 512, 512, nullptr, 0);
    // h1 = LN(h + att_out), in place in Hc
    ln_fused<<<R / 4, 256, 0, stream>>>(Hc, AOc, gb, 0, Hc);
    // FF1 with SiLU
    gemm_bt<1, 0><<<dim3(16, R / 128), blk, 0, stream>>>(Hc, Wf1T, big, 2048, 512, nullptr, 0);
    // FF2
    gemm_bt<0, 0><<<dim3(4, R / 128), blk, 0, stream>>>(big, Wf2T, AOc, 512, 2048, nullptr, 0);
    // h2 = LN(h1 + ff), in place in Hc
    ln_fused<<<R / 4, 256, 0, stream>>>(Hc, AOc, gb, 1024, Hc);
    // output proj -> d_out rows [rowoff, rowoff+R)
    gemm_bt<0, 1><<<dim3(1, R / 128), blk, 0, stream>>>(Hc, WouT, d_out, 128, 512, flag, rowoff);
  }
}

// Round 5
// 1955.658 us; speedup vs baseline: 1.1348x; 1.1333x over previous
//
#include <hip/hip_runtime.h>
#include <hip/hip_bf16.h>
#include <cstdint>
#include <cstddef>

typedef __bf16 bf16;
typedef __bf16 bf16x8 __attribute__((ext_vector_type(8)));
typedef float  f32x4  __attribute__((ext_vector_type(4)));
typedef float  f32x16 __attribute__((ext_vector_type(16)));

#define DEVI static __device__ __forceinline__

DEVI void gload_lds16(const void* g, void* l) {
  __builtin_amdgcn_global_load_lds(
      (const __attribute__((address_space(1))) uint32_t*)(uintptr_t)g,
      (__attribute__((address_space(3))) uint32_t*)(uint32_t)(uintptr_t)l,
      16, 0, 0);
}

DEVI float ldf(const void* p, size_t i, bool isbf) {
  return isbf ? (float)((const bf16*)p)[i] : ((const float*)p)[i];
}

// ---------------- dtype probe: bf16 data has small magnitudes; fp32 data
// re-read as bf16 yields huge/NaN values from mantissa halves. ----------------
__global__ void probe_dtype(const void* w, int* flag) {
  int tid = threadIdx.x;
  const bf16* p = (const bf16*)w;
  float mx = 0.f;
  for (int i = tid; i < 2048; i += 64) {
    float v = fabsf((float)p[i]);
    if (!(v < 1e30f)) v = 1e30f;  // NaN/Inf -> large
    mx = fmaxf(mx, v);
  }
#pragma unroll
  for (int d = 32; d; d >>= 1) mx = fmaxf(mx, __shfl_xor(mx, d, 64));
  if (tid == 0) *flag = (mx < 100.f) ? 1 : 0;  // 1 => inputs are bf16
}

__global__ void convert_bf16(const void* src, size_t eoff, bf16* dst, int n,
                             const int* flag) {
  int i = (blockIdx.x * 256 + threadIdx.x) * 8;
  if (i >= n) return;
  if (*flag) {
    *(uint4*)(dst + i) = *(const uint4*)((const bf16*)src + eoff + i);
  } else {
    const float* s = (const float*)src + eoff + i;
    float4 a = *(const float4*)s;
    float4 b = *(const float4*)(s + 4);
    bf16 o[8] = {(bf16)a.x, (bf16)a.y, (bf16)a.z, (bf16)a.w,
                 (bf16)b.x, (bf16)b.y, (bf16)b.z, (bf16)b.w};
    *(uint4*)(dst + i) = *(const uint4*)o;
  }
}

// canonical f32 copy of a (possibly bf16) input
__global__ void convert_f32(const void* src, float* dst, int n, const int* flag) {
  int i = blockIdx.x * 256 + threadIdx.x;
  if (i >= n) return;
  dst[i] = ldf(src, i, *flag != 0);
}

// WT[n][k] = W[k][n]; W is [K][N] row-major, WT is [N][K] row-major (bf16 out)
__global__ void transpose_w(const void* W, bf16* WT, int K, int N, const int* flag) {
  int idx = blockIdx.x * 256 + threadIdx.x;
  if (idx >= K * N) return;
  int n = idx / K, k = idx - n * K;
  WT[idx] = (bf16)ldf(W, (size_t)k * N + n, *flag != 0);
}

// F[pair][h] = sum_p dt[d][p]*pt[phi][p]*Wb[p][h], pair = d*512+phi
__global__ __launch_bounds__(256) void build_F(const float* __restrict__ dt32,
                                               const float* __restrict__ pt32,
                                               const float* __restrict__ Wb32,
                                               bf16* __restrict__ F) {
  __shared__ float WbS[256];
  WbS[threadIdx.x] = Wb32[threadIdx.x];
  __syncthreads();
  int pair = blockIdx.x * 256 + threadIdx.x;
  int d = pair >> 9, ph = pair & 511;
  const float4* dtv = (const float4*)(dt32 + (size_t)d * 32);
  const float4* ptv = (const float4*)(pt32 + (size_t)ph * 32);
  float acc[8] = {0, 0, 0, 0, 0, 0, 0, 0};
#pragma unroll
  for (int q = 0; q < 8; ++q) {
    float4 a = dtv[q], b = ptv[q];
    float pe[4] = {a.x * b.x, a.y * b.y, a.z * b.z, a.w * b.w};
#pragma unroll
    for (int e = 0; e < 4; ++e)
#pragma unroll
      for (int hh = 0; hh < 8; ++hh) acc[hh] += pe[e] * WbS[(q * 4 + e) * 8 + hh];
  }
  bf16 o[8];
#pragma unroll
  for (int hh = 0; hh < 8; ++hh) o[hh] = (bf16)acc[hh];
  *(uint4*)(F + (size_t)pair * 8) = *(const uint4*)o;
}

// C[(row0+M), N] = A[M,K] @ BT[N,K]^T, 128x128 tile, BK=64 (two 32-col LDS
// halves, 64-B rows), 4 waves, 16x16x32 bf16 MFMA, gload_lds staging.
// A_CONV: reg-stage A with runtime dtype conversion (for raw input x).
template <int DO_SILU, int OUT_DUAL, int A_CONV>
__global__ __launch_bounds__(256) void gemm_bt(const void* __restrict__ Av,
                                               size_t aoff,
                                               const bf16* __restrict__ BT,
                                               void* __restrict__ Cv, int N, int K,
                                               const int* flag, size_t row0) {
  __shared__ bf16 As[2][128 * 32];
  __shared__ bf16 Bs[2][128 * 32];
  const int bn = blockIdx.x * 128;
  const int bm = blockIdx.y * 128;
  const int tid = threadIdx.x;
  const int lane = tid & 63;
  const int wave = tid >> 6;
  const int wr = (wave >> 1) * 64, wc = (wave & 1) * 64;
  const int srow = tid >> 2;            // 0..63
  const int scol = (tid & 3) * 8;       // element col within 32-wide half
  const size_t sK = (size_t)K;
  const int kq = (lane >> 4) * 8;
  const int fr = lane & 15;
  const bf16* A = (const bf16*)Av + (A_CONV ? 0 : aoff);
  const bool a_isbf = A_CONV ? (*flag != 0) : true;
  f32x4 acc[4][4] = {};
  for (int k0 = 0; k0 < K; k0 += 64) {
    bf16x8 aval[2][2];
    if (A_CONV) {
      // load+convert A to regs before the barrier (overlap with prev compute)
#pragma unroll
      for (int h = 0; h < 2; ++h)
#pragma unroll
        for (int p = 0; p < 2; ++p) {
          size_t eidx = aoff + (size_t)(bm + p * 64 + srow) * sK + k0 + h * 32 + scol;
          if (a_isbf) {
            aval[h][p] = *(const bf16x8*)((const bf16*)Av + eidx);
          } else {
            const float* s = (const float*)Av + eidx;
            float4 a = *(const float4*)s;
            float4 b = *(const float4*)(s + 4);
            bf16x8 o;
            o[0] = (bf16)a.x; o[1] = (bf16)a.y; o[2] = (bf16)a.z; o[3] = (bf16)a.w;
            o[4] = (bf16)b.x; o[5] = (bf16)b.y; o[6] = (bf16)b.z; o[7] = (bf16)b.w;
            aval[h][p] = o;
          }
        }
    }
    __syncthreads();  // previous tile fully consumed
    if (A_CONV) {
#pragma unroll
      for (int h = 0; h < 2; ++h)
#pragma unroll
        for (int p = 0; p < 2; ++p)
          *(bf16x8*)(&As[h][(p * 64 + srow) * 32 + scol]) = aval[h][p];
    } else {
#pragma unroll
      for (int h = 0; h < 2; ++h)
#pragma unroll
        for (int p = 0; p < 2; ++p)
          gload_lds16(A + (size_t)(bm + p * 64 + srow) * sK + k0 + h * 32 + scol,
                      &As[h][p * 2048] + (tid & 255) * 8);
    }
#pragma unroll
    for (int h = 0; h < 2; ++h)
#pragma unroll
      for (int p = 0; p < 2; ++p)
        gload_lds16(BT + (size_t)(bn + p * 64 + srow) * sK + k0 + h * 32 + scol,
                    &Bs[h][p * 2048] + (tid & 255) * 8);
    __syncthreads();
#pragma unroll
    for (int kh = 0; kh < 2; ++kh) {
      bf16x8 af[4], bfr[4];
#pragma unroll
      for (int i = 0; i < 4; ++i)
        af[i] = *(const bf16x8*)(&As[kh][(wr + i * 16 + fr) * 32 + kq]);
#pragma unroll
      for (int j = 0; j < 4; ++j)
        bfr[j] = *(const bf16x8*)(&Bs[kh][(wc + j * 16 + fr) * 32 + kq]);
#pragma unroll
      for (int i = 0; i < 4; ++i)
#pragma unroll
        for (int j = 0; j < 4; ++j)
          acc[i][j] = __builtin_amdgcn_mfma_f32_16x16x32_bf16(af[i], bfr[j], acc[i][j], 0, 0, 0);
    }
  }
  const int fq = (lane >> 4) * 4;
  const bool write_f32 = OUT_DUAL && flag && (*flag == 0);
#pragma unroll
  for (int i = 0; i < 4; ++i)
#pragma unroll
    for (int j = 0; j < 4; ++j)
#pragma unroll
      for (int r = 0; r < 4; ++r) {
        size_t row = row0 + (size_t)(bm + wr + i * 16 + fq + r);
        size_t col = (size_t)(bn + wc + j * 16 + fr);
        float v = acc[i][j][r];
        if (DO_SILU) v = v / (1.f + __expf(-v));
        if (OUT_DUAL && write_f32)
          ((float*)Cv)[row * N + col] = v;
        else
          ((bf16*)Cv)[row * N + col] = (bf16)v;
      }
}

// per-problem fused attention + bias gather: block = m (chunk-local), wave = head
__global__ __launch_bounds__(512) void attn_fused(const bf16* __restrict__ QKV,
                                                  const int* __restrict__ dist,
                                                  const int* __restrict__ phi,
                                                  const bf16* __restrict__ F,
                                                  bf16* __restrict__ O) {
  const int m = blockIdx.x;
  const int lane = threadIdx.x & 63;
  const int h = threadIdx.x >> 6;
  __shared__ bf16 Vs[8][32 * 64];
  __shared__ bf16 Ps[8][32 * 32];
  const size_t rowbase = (size_t)m * 32 * 1536;
  // stage V [32][64] (wave-private slice)
#pragma unroll
  for (int rr = 0; rr < 4; ++rr) {
    int e = rr * 512 + lane * 8;
    int i = e >> 6, c = e & 63;
    *(uint4*)&Vs[h][e] =
        *(const uint4*)(QKV + rowbase + (size_t)i * 1536 + 1024 + h * 64 + c);
  }
  const int fr = lane & 31;
  const int kq = (lane >> 5) * 8;
  bf16x8 qf[4], kf[4];
#pragma unroll
  for (int kk = 0; kk < 4; ++kk) {
    qf[kk] = *(const bf16x8*)(QKV + rowbase + (size_t)fr * 1536 + h * 64 + kk * 16 + kq);
    kf[kk] = *(const bf16x8*)(QKV + rowbase + (size_t)fr * 1536 + 512 + h * 64 + kk * 16 + kq);
  }
  f32x16 s = {};
#pragma unroll
  for (int kk = 0; kk < 4; ++kk)
    s = __builtin_amdgcn_mfma_f32_32x32x16_bf16(qf[kk], kf[kk], s, 0, 0, 0);
  // D layout: col j = lane&31, row i = (r&3)+8*(r>>2)+4*(lane>>5)
  const int* dmp = dist + (size_t)m * 1024;
  const int* pmp = phi + (size_t)m * 1024;
  const int ri = 4 * (lane >> 5);
  float p[16];
#pragma unroll
  for (int r = 0; r < 16; ++r) {
    int i = (r & 3) + 8 * (r >> 2) + ri;
    int e = i * 32 + fr;
    int d = dmp[e], ph = pmp[e];
    float bias = (float)F[((size_t)d * 512 + ph) * 8 + h];
    p[r] = s[r] * 0.125f + bias;
  }
#pragma unroll
  for (int r = 0; r < 16; ++r) {
    float mx = p[r];
#pragma unroll
    for (int d = 16; d; d >>= 1) mx = fmaxf(mx, __shfl_xor(mx, d, 64));
    float e = __expf(p[r] - mx);
    float sum = e;
#pragma unroll
    for (int d = 16; d; d >>= 1) sum += __shfl_xor(sum, d, 64);
    p[r] = e / sum;
  }
#pragma unroll
  for (int r = 0; r < 16; ++r) {
    int i = (r & 3) + 8 * (r >> 2) + ri;
    Ps[h][i * 32 + fr] = (bf16)p[r];
  }
  __syncthreads();  // order LDS P/V writes before cross-lane reads
  bf16x8 pf[2];
#pragma unroll
  for (int kk = 0; kk < 2; ++kk)
    pf[kk] = *(const bf16x8*)(&Ps[h][fr * 32 + kk * 16 + kq]);
  f32x16 o0 = {}, o1 = {};
#pragma unroll
  for (int kk = 0; kk < 2; ++kk) {
    bf16x8 v0, v1;
#pragma unroll
    for (int e = 0; e < 8; ++e) {
      v0[e] = Vs[h][(kk * 16 + kq + e) * 64 + fr];
      v1[e] = Vs[h][(kk * 16 + kq + e) * 64 + 32 + fr];
    }
    o0 = __builtin_amdgcn_mfma_f32_32x32x16_bf16(pf[kk], v0, o0, 0, 0, 0);
    o1 = __builtin_amdgcn_mfma_f32_32x32x16_bf16(pf[kk], v1, o1, 0, 0, 0);
  }
  bf16* op = O + (size_t)m * 32 * 512 + h * 64;
#pragma unroll
  for (int r = 0; r < 16; ++r) {
    int i = (r & 3) + 8 * (r >> 2) + ri;
    op[(size_t)i * 512 + fr] = (bf16)o0[r];
    op[(size_t)i * 512 + 32 + fr] = (bf16)o1[r];
  }
}

// out = LN(X+Y)*g+b ; one wave per 512-wide row (X==out aliasing is safe)
__global__ __launch_bounds__(256) void ln_fused(const bf16* __restrict__ X,
                                                const bf16* __restrict__ Y,
                                                const bf16* __restrict__ gb, int gboff,
                                                bf16* __restrict__ out) {
  const int row = blockIdx.x * 4 + (threadIdx.x >> 6);
  const int lane = threadIdx.x & 63;
  uint4 xr = *(const uint4*)(X + (size_t)row * 512 + lane * 8);
  uint4 yr = *(const uint4*)(Y + (size_t)row * 512 + lane * 8);
  const bf16* xe = (const bf16*)&xr;
  const bf16* ye = (const bf16*)&yr;
  float v[8];
  float sum = 0.f;
#pragma unroll
  for (int e = 0; e < 8; ++e) { v[e] = (float)xe[e] + (float)ye[e]; sum += v[e]; }
#pragma unroll
  for (int d = 32; d; d >>= 1) sum += __shfl_xor(sum, d, 64);
  float mean = sum * (1.f / 512.f);
  float var = 0.f;
#pragma unroll
  for (int e = 0; e < 8; ++e) { float t = v[e] - mean; var += t * t; }
#pragma unroll
  for (int d = 32; d; d >>= 1) var += __shfl_xor(var, d, 64);
  float rstd = rsqrtf(var * (1.f / 512.f) + 1e-5f);
  uint4 gr = *(const uint4*)(gb + gboff + lane * 8);
  uint4 br = *(const uint4*)(gb + gboff + 512 + lane * 8);
  const bf16* ge = (const bf16*)&gr;
  const bf16* be = (const bf16*)&br;
  bf16 o[8];
#pragma unroll
  for (int e = 0; e < 8; ++e)
    o[e] = (bf16)((v[e] - mean) * rstd * (float)ge[e] + (float)be[e]);
  *(uint4*)(out + (size_t)row * 512 + lane * 8) = *(const uint4*)o;
}

extern "C" void kernel_launch(void* const* d_in, const int* in_sizes, int n_in,
                              void* d_out, int out_size, void* d_ws, size_t ws_size,
                              hipStream_t stream) {
  const int T = 131072;  // B*N*NH total rows
  const void* x    = d_in[0];
  const int*  dist = (const int*)d_in[1];
  const int*  phiI = (const int*)d_in[2];
  const void* Win  = d_in[3];
  const void* dtab = d_in[4];
  const void* ptab = d_in[5];
  const void* Wb   = d_in[6];
  const void* Wq   = d_in[7];
  const void* Wk   = d_in[8];
  const void* Wv   = d_in[9];
  const void* Wo   = d_in[10];
  const void* Wf1  = d_in[11];
  const void* Wf2  = d_in[12];
  const void* g1   = d_in[13];
  const void* b1   = d_in[14];
  const void* g2   = d_in[15];
  const void* b2   = d_in[16];
  const void* Wout = d_in[17];
  (void)in_sizes; (void)n_in; (void)out_size;

  // ---- adaptive chunking: largest power-of-two row chunk that fits ws
  const size_t FIXED = (size_t)16 << 20;   // weights + F-table + slack
  int R = 131072;
  while (R > 1024 && FIXED + (size_t)R * 7168 > ws_size) R >>= 1;
  const int MC = R / 32;
  const int NCHUNK = T / R;

  char* wsb = (char*)d_ws;
  size_t off = 0;
  auto alloc = [&](size_t bytes) {
    char* p = wsb + off;
    off += (bytes + 511) & ~(size_t)511;
    return p;
  };
  int*  flag = (int*)alloc(4);
  bf16* gb   = (bf16*)alloc(2048 * 2);
  float* dt32 = (float*)alloc((size_t)512 * 32 * 4);
  float* pt32 = (float*)alloc((size_t)512 * 32 * 4);
  float* Wb32 = (float*)alloc(256 * 4);
  bf16* WinT = (bf16*)alloc((size_t)512 * 128 * 2);
  bf16* QKVT = (bf16*)alloc((size_t)1536 * 512 * 2);
  bf16* WoT  = (bf16*)alloc((size_t)512 * 512 * 2);
  bf16* Wf1T = (bf16*)alloc((size_t)2048 * 512 * 2);
  bf16* Wf2T = (bf16*)alloc((size_t)512 * 2048 * 2);
  bf16* WouT = (bf16*)alloc((size_t)128 * 512 * 2);
  bf16* Ftab = (bf16*)alloc((size_t)262144 * 8 * 2);     // 4 MB
  bf16* Hc   = (bf16*)alloc((size_t)R * 512 * 2);
  bf16* big  = (bf16*)alloc((size_t)R * 2048 * 2);       // QKV (1536) / FF1 (2048)
  bf16* Oc   = (bf16*)alloc((size_t)R * 512 * 2);
  bf16* AOc  = (bf16*)alloc((size_t)R * 512 * 2);

  probe_dtype<<<1, 64, 0, stream>>>(Win, flag);
  convert_bf16<<<1, 256, 0, stream>>>(g1, 0, gb + 0, 512, flag);
  convert_bf16<<<1, 256, 0, stream>>>(b1, 0, gb + 512, 512, flag);
  convert_bf16<<<1, 256, 0, stream>>>(g2, 0, gb + 1024, 512, flag);
  convert_bf16<<<1, 256, 0, stream>>>(b2, 0, gb + 1536, 512, flag);
  convert_f32<<<64, 256, 0, stream>>>(dtab, dt32, 512 * 32, flag);
  convert_f32<<<64, 256, 0, stream>>>(ptab, pt32, 512 * 32, flag);
  convert_f32<<<1, 256, 0, stream>>>(Wb, Wb32, 256, flag);
  transpose_w<<<(512 * 128 + 255) / 256, 256, 0, stream>>>(Win, WinT, 128, 512, flag);
  transpose_w<<<(512 * 512 + 255) / 256, 256, 0, stream>>>(Wq, QKVT, 512, 512, flag);
  transpose_w<<<(512 * 512 + 255) / 256, 256, 0, stream>>>(Wk, QKVT + 512 * 512, 512, 512, flag);
  transpose_w<<<(512 * 512 + 255) / 256, 256, 0, stream>>>(Wv, QKVT + 1024 * 512, 512, 512, flag);
  transpose_w<<<(512 * 512 + 255) / 256, 256, 0, stream>>>(Wo, WoT, 512, 512, flag);
  transpose_w<<<(2048 * 512 + 255) / 256, 256, 0, stream>>>(Wf1, Wf1T, 512, 2048, flag);
  transpose_w<<<(2048 * 512 + 255) / 256, 256, 0, stream>>>(Wf2, Wf2T, 2048, 512, flag);
  transpose_w<<<(128 * 512 + 255) / 256, 256, 0, stream>>>(Wout, WouT, 512, 128, flag);
  build_F<<<262144 / 256, 256, 0, stream>>>(dt32, pt32, Wb32, Ftab);

  dim3 blk(256);
  for (int c = 0; c < NCHUNK; ++c) {
    const size_t rowoff = (size_t)c * R;
    const size_t moff = (size_t)c * MC;
    // input proj with fused dtype conversion: Hc = x[chunk] @ W_in
    gemm_bt<0, 0, 1><<<dim3(4, R / 128), blk, 0, stream>>>(
        x, rowoff * 128, WinT, Hc, 512, 128, flag, 0);
    // QKV chunk
    gemm_bt<0, 0, 0><<<dim3(12, R / 128), blk, 0, stream>>>(
        Hc, 0, QKVT, big, 1536, 512, nullptr, 0);
    // attention with fused bias gather
    attn_fused<<<MC, 512, 0, stream>>>(big, dist + moff * 1024, phiI + moff * 1024,
                                       Ftab, Oc);
    // att_out chunk
    gemm_bt<0, 0, 0><<<dim3(4, R / 128), blk, 0, stream>>>(
        Oc, 0, WoT, AOc, 512, 512, nullptr, 0);
    // h1 = LN(h + att_out), in place in Hc
    ln_fused<<<R / 4, 256, 0, stream>>>(Hc, AOc, gb, 0, Hc);
    // FF1 with SiLU
    gemm_bt<1, 0, 0><<<dim3(16, R / 128), blk, 0, stream>>>(
        Hc, 0, Wf1T, big, 2048, 512, nullptr, 0);
    // FF2
    gemm_bt<0, 0, 0><<<dim3(4, R / 128), blk, 0, stream>>>(
        big, 0, Wf2T, AOc, 512, 2048, nullptr, 0);
    // h2 = LN(h1 + ff), in place in Hc
    ln_fused<<<R / 4, 256, 0, stream>>>(Hc, AOc, gb, 1024, Hc);
    // output proj -> d_out rows [rowoff, rowoff+R)
    gemm_bt<0, 1, 0><<<dim3(1, R / 128), blk, 0, stream>>>(
        Hc, 0, WouT, d_out, 128, 512, flag, rowoff);
  }
}